// Round 8
// baseline (598.291 us; speedup 1.0000x reference)
//
#include <hip/hip_runtime.h>
#include <hip/hip_bf16.h>
#include <math.h>

// ---------------------------------------------------------------------------
// QuantumEnhancedFlow — round 8
//   qkernel : product-state init + packed-f32 complex math + ds_swizzle lane
//             exchanges (unchanged).
//   prep    : split fp32 weights into hi/lo bf16 (unchanged).
//   mlpkernel: split-bf16 MFMA MLP, 512 thr / 8 waves, NT=4, P/Q register
//             double-buffer of W. r7 fixed spills via waves_per_eu(2,2)
//             (VGPR 104, WRITE 0.13MB) but capped at 8 waves/CU -> MfmaUtil 15%.
//             r8: VGPR 104 fits 128 -> amdgpu_waves_per_eu(4,4): 2 blocks/CU,
//             16 waves/CU = TLP x2 on top of the working dbuf ILP.
// ws layout: [0,8MB) enh fp32 ; [8MB,10.5MB) W hi/lo bf16
// ---------------------------------------------------------------------------

#define N_SAMPLES 32768
#define FEAT 64

typedef unsigned short u16;
typedef __attribute__((ext_vector_type(2))) float f32x2;
typedef __attribute__((ext_vector_type(8))) short bf16x8_t;
typedef __attribute__((ext_vector_type(4))) float f32x4_t;

__device__ __forceinline__ u16 f2bf(float v) {
    __hip_bfloat16 b = __float2bfloat16(v);
    return __builtin_bit_cast(u16, b);
}
__device__ __forceinline__ float bf2f(u16 u) {
    return __bfloat162float(__builtin_bit_cast(__hip_bfloat16, u));
}

// ===========================================================================
// qkernel
// ===========================================================================
__device__ __forceinline__ f32x2 cmul(f32x2 a, f32x2 b) {
    f32x2 r = (f32x2){a.x, a.x} * b;
    f32x2 bs = __builtin_shufflevector(b, b, 1, 0);
    r = (f32x2){-a.y, a.y} * bs + r;
    return r;
}
// lane exchange lane^M: ds_swizzle (1 DS op, zero VALU addr) for M<32
template<int M>
__device__ __forceinline__ float xexf(float v) {
    if constexpr (M < 32) {
        constexpr int pat = (M << 10) | 0x1f;   // BitMode xor=M, and=0x1f
        return __uint_as_float(__builtin_amdgcn_ds_swizzle(__float_as_uint(v), pat));
    } else {
        return __shfl_xor(v, 32, 64);
    }
}
template<int M>
__device__ __forceinline__ f32x2 xex2(f32x2 v) {
    return (f32x2){xexf<M>(v.x), xexf<M>(v.y)};
}

template<int Q>
__device__ __forceinline__ void rot_gate(f32x2 (&amp)[16],
                                         f32x2 g00, f32x2 g01, f32x2 g10, f32x2 g11,
                                         int lane) {
    if constexpr (Q < 4) {
        #pragma unroll
        for (int t = 0; t < 16; ++t) {
            if ((t & (1 << Q)) == 0) {
                const int t1 = t | (1 << Q);
                f32x2 a = amp[t], b = amp[t1];
                amp[t]  = cmul(g00, a) + cmul(g01, b);
                amp[t1] = cmul(g10, a) + cmul(g11, b);
            }
        }
    } else {
        constexpr int xm = 1 << (Q - 4);
        const bool hi = (lane >> (Q - 4)) & 1;
        f32x2 ga = hi ? g11 : g00;
        f32x2 gb = hi ? g10 : g01;
        #pragma unroll
        for (int t = 0; t < 16; ++t) {
            f32x2 b = xex2<xm>(amp[t]);
            amp[t] = cmul(ga, amp[t]) + cmul(gb, b);
        }
    }
}

template<int C, int T>
__device__ __forceinline__ void cx_local(f32x2 (&amp)[16]) {
    #pragma unroll
    for (int t = 0; t < 16; ++t) {
        if (((t >> C) & 1) && !((t >> T) & 1)) {
            const int t1 = t | (1 << T);
            f32x2 tmp = amp[t]; amp[t] = amp[t1]; amp[t1] = tmp;
        }
    }
}
__device__ __forceinline__ void cx_3_4(f32x2 (&amp)[16]) {
    #pragma unroll
    for (int t = 0; t < 16; ++t)
        if ((t >> 3) & 1) amp[t] = xex2<1>(amp[t]);
}
template<int CL, int TL>
__device__ __forceinline__ void cx_lane(f32x2 (&amp)[16], int lane) {
    const bool ctrl = (lane >> CL) & 1;
    #pragma unroll
    for (int t = 0; t < 16; ++t) {
        f32x2 v = xex2<(1 << TL)>(amp[t]);
        if (ctrl) amp[t] = v;
    }
}
__device__ __forceinline__ void cx_9_0(f32x2 (&amp)[16], int lane) {
    const bool ctrl = (lane >> 5) & 1;
    #pragma unroll
    for (int t = 0; t < 16; t += 2) {
        f32x2 a = amp[t], b = amp[t + 1];
        amp[t]     = ctrl ? b : a;
        amp[t + 1] = ctrl ? a : b;
    }
}

__global__ __launch_bounds__(256)
void qkernel(const float* __restrict__ x, const float* __restrict__ theta,
             float* __restrict__ enh) {
    __shared__ f32x2 gbuf[20][4];
    const int tid = threadIdx.x;
    if (tid < 20) {
        const int base = tid * 3;
        float s1, c1, s2, c2, sz, cz;
        sincosf(0.5f * theta[base + 0], &s1, &c1);
        sincosf(0.5f * theta[base + 1], &s2, &c2);
        sincosf(0.5f * theta[base + 2], &sz, &cz);
        f32x2 m00 = (f32x2){ c2*c1,  s2*s1};
        f32x2 m01 = (f32x2){-s2*c1, -c2*s1};
        f32x2 m10 = (f32x2){ s2*c1, -c2*s1};
        f32x2 m11 = (f32x2){ c2*c1, -s2*s1};
        f32x2 e0 = (f32x2){cz, -sz}, e1 = (f32x2){cz, sz};
        gbuf[tid][0] = cmul(e0, m00);
        gbuf[tid][1] = cmul(e0, m01);
        gbuf[tid][2] = cmul(e1, m10);
        gbuf[tid][3] = cmul(e1, m11);
    }
    __syncthreads();

    const int lane = tid & 63;
    const int s = blockIdx.x * 4 + (tid >> 6);
    const float xr = x[s * FEAT + lane];

    const float inv = 1.0f / sqrtf(fmaf(xr, xr, 1.0f));
    const float cq = inv, sq = xr * inv;

    float csv[10], snv[10];
    #pragma unroll
    for (int i = 0; i < 10; ++i) {
        csv[i] = __shfl(cq, i, 64);
        snv[i] = __shfl(sq, i, 64);
    }

    float lf = ((lane >> 0) & 1) ? snv[4] : csv[4];
    lf *= ((lane >> 1) & 1) ? snv[5] : csv[5];
    lf *= ((lane >> 2) & 1) ? snv[6] : csv[6];
    lf *= ((lane >> 3) & 1) ? snv[7] : csv[7];
    lf *= ((lane >> 4) & 1) ? snv[8] : csv[8];
    lf *= ((lane >> 5) & 1) ? snv[9] : csv[9];
    float l01[4], l23[4];
    l01[0] = csv[0]*csv[1]; l01[1] = snv[0]*csv[1];
    l01[2] = csv[0]*snv[1]; l01[3] = snv[0]*snv[1];
    l23[0] = csv[2]*csv[3]; l23[1] = snv[2]*csv[3];
    l23[2] = csv[2]*snv[3]; l23[3] = snv[2]*snv[3];

    f32x2 amp[16];
    #pragma unroll
    for (int t = 0; t < 16; ++t)
        amp[t] = (f32x2){lf * l01[t & 3] * l23[(t >> 2) & 3], 0.f};

    #pragma unroll
    for (int l = 0; l < 2; ++l) {
        const f32x2* gl = &gbuf[l * 10][0];
        #define ROT(Q) rot_gate<Q>(amp, gl[Q*4+0], gl[Q*4+1], gl[Q*4+2], gl[Q*4+3], lane);
        ROT(0) ROT(1) ROT(2) ROT(3) ROT(4) ROT(5) ROT(6) ROT(7) ROT(8) ROT(9)
        #undef ROT
        cx_local<0,1>(amp); cx_local<1,2>(amp); cx_local<2,3>(amp);
        cx_3_4(amp);
        cx_lane<0,1>(amp, lane); cx_lane<1,2>(amp, lane); cx_lane<2,3>(amp, lane);
        cx_lane<3,4>(amp, lane); cx_lane<4,5>(amp, lane);
        cx_9_0(amp, lane);
    }

    float p[16];
    #pragma unroll
    for (int t = 0; t < 16; ++t) p[t] = amp[t].x*amp[t].x + amp[t].y*amp[t].y;
    float o[10];
    #pragma unroll
    for (int i = 0; i < 4; ++i) {
        float acc = 0.f;
        #pragma unroll
        for (int t = 0; t < 16; ++t) acc += ((t >> i) & 1) ? -p[t] : p[t];
        o[i] = acc;
    }
    float ptot = 0.f;
    #pragma unroll
    for (int t = 0; t < 16; ++t) ptot += p[t];
    #pragma unroll
    for (int i = 4; i < 10; ++i) o[i] = ((lane >> (i - 4)) & 1) ? -ptot : ptot;
    #pragma unroll
    for (int i = 0; i < 10; ++i) {
        #pragma unroll
        for (int b = 1; b < 64; b <<= 1) o[i] += __shfl_xor(o[i], b, 64);
    }
    float outv = xr;
    #pragma unroll
    for (int i = 0; i < 10; ++i) if (lane == i) outv = o[i];
    enh[s * FEAT + lane] = outv;
}

// ===========================================================================
// prep: split fp32 W into hi/lo bf16 arrays
// ===========================================================================
__global__ __launch_bounds__(256)
void prep(const float* __restrict__ W_in, const float* __restrict__ W_h,
          const float* __restrict__ W_out,
          u16* __restrict__ win_hi, u16* __restrict__ win_lo,
          u16* __restrict__ wh_hi,  u16* __restrict__ wh_lo,
          u16* __restrict__ wout_hi,u16* __restrict__ wout_lo) {
    const int i = blockIdx.x * 256 + threadIdx.x;   // grid covers 622592 exactly
    float v; u16 *ph, *pl; int off;
    if (i < 32768)        { v = W_in[i];          ph = win_hi;  pl = win_lo;  off = i; }
    else if (i < 557056)  { off = i - 32768;  v = W_h[off];   ph = wh_hi;   pl = wh_lo;  }
    else                  { off = i - 557056; v = W_out[off]; ph = wout_hi; pl = wout_lo; }
    const u16 hi = f2bf(v);
    const u16 lo = f2bf(v - bf2f(hi));
    ph[off] = hi; pl[off] = lo;
}

// ===========================================================================
// MFMA MLP — 8 waves/block, NT cols-tiles/wave, explicit P/Q W double-buffer
//   LDS h hi/lo [32][512] bf16, XOR-swizzled:
//     (m,k) stored at m*K + ((k>>3)^(m&7))*8 + (k&7)
// ===========================================================================
__device__ __forceinline__ float fast_tanh(float x) {
    // tanh(x) = 1 - 2/(exp(2x)+1); overflow-safe (e=inf -> 1, e=0 -> -1)
    const float e = __expf(2.0f * x);
    return 1.0f - 2.0f * __builtin_amdgcn_rcpf(e + 1.0f);
}

template<int K, int NT>
__device__ __forceinline__ void gemm_frag(
        const u16* __restrict__ Whi, const u16* __restrict__ Wlo,
        const u16* hHi, const u16* hLo, int lane, int colbase,
        f32x4_t (&acc)[2][NT]) {
    constexpr int KS = K / 32;
    const int l15 = lane & 15, l4 = lane >> 4, l7 = lane & 7;

    #pragma unroll
    for (int mt = 0; mt < 2; ++mt)
        #pragma unroll
        for (int nt = 0; nt < NT; ++nt) acc[mt][nt] = (f32x4_t)0.f;

    int woff[NT];
    #pragma unroll
    for (int nt = 0; nt < NT; ++nt)
        woff[nt] = (colbase + nt * 16 + l15) * K + l4 * 8;

    // P holds W(ks), Q holds W(ks+1)
    bf16x8_t pH[NT], pL[NT], qH[NT], qL[NT];
    #pragma unroll
    for (int nt = 0; nt < NT; ++nt) {
        pH[nt] = *(const bf16x8_t*)&Whi[woff[nt]];
        pL[nt] = *(const bf16x8_t*)&Wlo[woff[nt]];
        qH[nt] = *(const bf16x8_t*)&Whi[woff[nt] + 32];
        qL[nt] = *(const bf16x8_t*)&Wlo[woff[nt] + 32];
    }

    int ks = 0;
    #pragma unroll 1
    for (; ks + 2 < KS; ks += 2) {
        // ---- compute ks with P ----
        bf16x8_t aH[2], aL[2];
        #pragma unroll
        for (int mt = 0; mt < 2; ++mt) {
            const int off = (mt * 16 + l15) * K + (((ks * 4 + l4) ^ l7) * 8);
            aH[mt] = *(const bf16x8_t*)&hHi[off];
            aL[mt] = *(const bf16x8_t*)&hLo[off];
        }
        #pragma unroll
        for (int nt = 0; nt < NT; ++nt)
            #pragma unroll
            for (int mt = 0; mt < 2; ++mt) {
                acc[mt][nt] = __builtin_amdgcn_mfma_f32_16x16x32_bf16(aH[mt], pH[nt], acc[mt][nt], 0, 0, 0);
                acc[mt][nt] = __builtin_amdgcn_mfma_f32_16x16x32_bf16(aH[mt], pL[nt], acc[mt][nt], 0, 0, 0);
                acc[mt][nt] = __builtin_amdgcn_mfma_f32_16x16x32_bf16(aL[mt], pH[nt], acc[mt][nt], 0, 0, 0);
            }
        // ---- prefetch P <- ks+2 (hides under Q's MFMAs) ----
        #pragma unroll
        for (int nt = 0; nt < NT; ++nt) {
            pH[nt] = *(const bf16x8_t*)&Whi[woff[nt] + (ks + 2) * 32];
            pL[nt] = *(const bf16x8_t*)&Wlo[woff[nt] + (ks + 2) * 32];
        }
        // ---- compute ks+1 with Q ----
        #pragma unroll
        for (int mt = 0; mt < 2; ++mt) {
            const int off = (mt * 16 + l15) * K + ((((ks + 1) * 4 + l4) ^ l7) * 8);
            aH[mt] = *(const bf16x8_t*)&hHi[off];
            aL[mt] = *(const bf16x8_t*)&hLo[off];
        }
        #pragma unroll
        for (int nt = 0; nt < NT; ++nt)
            #pragma unroll
            for (int mt = 0; mt < 2; ++mt) {
                acc[mt][nt] = __builtin_amdgcn_mfma_f32_16x16x32_bf16(aH[mt], qH[nt], acc[mt][nt], 0, 0, 0);
                acc[mt][nt] = __builtin_amdgcn_mfma_f32_16x16x32_bf16(aH[mt], qL[nt], acc[mt][nt], 0, 0, 0);
                acc[mt][nt] = __builtin_amdgcn_mfma_f32_16x16x32_bf16(aL[mt], qH[nt], acc[mt][nt], 0, 0, 0);
            }
        // ---- prefetch Q <- ks+3 (hides under next P's MFMAs) ----
        #pragma unroll
        for (int nt = 0; nt < NT; ++nt) {
            qH[nt] = *(const bf16x8_t*)&Whi[woff[nt] + (ks + 3) * 32];
            qL[nt] = *(const bf16x8_t*)&Wlo[woff[nt] + (ks + 3) * 32];
        }
    }
    // ---- epilogue pair: compute ks (P) and ks+1 (Q), no prefetch ----
    {
        bf16x8_t aH[2], aL[2];
        #pragma unroll
        for (int mt = 0; mt < 2; ++mt) {
            const int off = (mt * 16 + l15) * K + (((ks * 4 + l4) ^ l7) * 8);
            aH[mt] = *(const bf16x8_t*)&hHi[off];
            aL[mt] = *(const bf16x8_t*)&hLo[off];
        }
        #pragma unroll
        for (int nt = 0; nt < NT; ++nt)
            #pragma unroll
            for (int mt = 0; mt < 2; ++mt) {
                acc[mt][nt] = __builtin_amdgcn_mfma_f32_16x16x32_bf16(aH[mt], pH[nt], acc[mt][nt], 0, 0, 0);
                acc[mt][nt] = __builtin_amdgcn_mfma_f32_16x16x32_bf16(aH[mt], pL[nt], acc[mt][nt], 0, 0, 0);
                acc[mt][nt] = __builtin_amdgcn_mfma_f32_16x16x32_bf16(aL[mt], pH[nt], acc[mt][nt], 0, 0, 0);
            }
        #pragma unroll
        for (int mt = 0; mt < 2; ++mt) {
            const int off = (mt * 16 + l15) * K + ((((ks + 1) * 4 + l4) ^ l7) * 8);
            aH[mt] = *(const bf16x8_t*)&hHi[off];
            aL[mt] = *(const bf16x8_t*)&hLo[off];
        }
        #pragma unroll
        for (int nt = 0; nt < NT; ++nt)
            #pragma unroll
            for (int mt = 0; mt < 2; ++mt) {
                acc[mt][nt] = __builtin_amdgcn_mfma_f32_16x16x32_bf16(aH[mt], qH[nt], acc[mt][nt], 0, 0, 0);
                acc[mt][nt] = __builtin_amdgcn_mfma_f32_16x16x32_bf16(aH[mt], qL[nt], acc[mt][nt], 0, 0, 0);
                acc[mt][nt] = __builtin_amdgcn_mfma_f32_16x16x32_bf16(aL[mt], qH[nt], acc[mt][nt], 0, 0, 0);
            }
    }
}

template<int NT>
__device__ __forceinline__ void write_h(
        f32x4_t (&acc)[2][NT], const float* __restrict__ bias,
        u16* hHi, u16* hLo, int lane, int colbase) {
    const int l15 = lane & 15, l4 = lane >> 4;
    #pragma unroll
    for (int nt = 0; nt < NT; ++nt) {
        const int n = colbase + nt * 16 + l15;
        const float b = bias[n];
        #pragma unroll
        for (int mt = 0; mt < 2; ++mt)
            #pragma unroll
            for (int r = 0; r < 4; ++r) {
                const int m = mt * 16 + l4 * 4 + r;
                const float v = fast_tanh(acc[mt][nt][r] + b);
                const u16 hi = f2bf(v);
                const u16 lo = f2bf(v - bf2f(hi));
                const int blk = (n >> 3) ^ (m & 7);
                const int off = m * 512 + blk * 8 + (n & 7);
                hHi[off] = hi; hLo[off] = lo;
            }
    }
}

__global__ __attribute__((amdgpu_waves_per_eu(4, 4))) __launch_bounds__(512)
void mlpkernel(const float* __restrict__ enh,
               const u16* __restrict__ win_hi, const u16* __restrict__ win_lo,
               const float* __restrict__ b_in,
               const u16* __restrict__ wh_hi,  const u16* __restrict__ wh_lo,
               const float* __restrict__ b_h,
               const u16* __restrict__ wout_hi,const u16* __restrict__ wout_lo,
               const float* __restrict__ b_out,
               float* __restrict__ out) {
    __shared__ u16 hHi[32 * 512];
    __shared__ u16 hLo[32 * 512];
    const int tid = threadIdx.x;
    const int lane = tid & 63, w = tid >> 6;      // 8 waves
    const int row0 = blockIdx.x * 32;

    // ---- stage enhanced[32][64] -> LDS hi/lo (K=64 layout, swizzled) ----
    {
        const int r = tid >> 4, c0 = (tid & 15) * 4;   // 512 thr * float4 = 2048
        const float4 v = *(const float4*)&enh[(row0 + r) * FEAT + c0];
        const float vv[4] = {v.x, v.y, v.z, v.w};
        u16 vh[4], vl[4];
        #pragma unroll
        for (int j = 0; j < 4; ++j) {
            vh[j] = f2bf(vv[j]);
            vl[j] = f2bf(vv[j] - bf2f(vh[j]));
        }
        const int off = r * 64 + (((c0 >> 3) ^ (r & 7)) * 8) + (c0 & 7);
        *(ushort4*)&hHi[off] = *(ushort4*)vh;
        *(ushort4*)&hLo[off] = *(ushort4*)vl;
    }
    __syncthreads();

    f32x4_t acc[2][4];
    gemm_frag<64, 4>(win_hi, win_lo, hHi, hLo, lane, w * 64, acc);
    __syncthreads();
    write_h<4>(acc, b_in, hHi, hLo, lane, w * 64);
    __syncthreads();
    gemm_frag<512, 4>(wh_hi, wh_lo, hHi, hLo, lane, w * 64, acc);
    __syncthreads();
    write_h<4>(acc, b_h, hHi, hLo, lane, w * 64);
    __syncthreads();
    gemm_frag<512, 4>(wh_hi + 262144, wh_lo + 262144, hHi, hLo, lane, w * 64, acc);
    __syncthreads();
    write_h<4>(acc, b_h + 512, hHi, hLo, lane, w * 64);
    __syncthreads();
    f32x4_t acc2[2][1];
    gemm_frag<512, 1>(wout_hi, wout_lo, hHi, hLo, lane, w * 16, acc2);
    __syncthreads();

    float* f = (float*)hHi;     // reuse LDS: out tile [32][128] fp32 (16 KB)
    {
        const int l15 = lane & 15, l4 = lane >> 4;
        const int n = w * 16 + l15;
        const float b = b_out[n];
        #pragma unroll
        for (int mt = 0; mt < 2; ++mt)
            #pragma unroll
            for (int r = 0; r < 4; ++r) {
                const int m = mt * 16 + l4 * 4 + r;
                f[m * 128 + n] = acc2[mt][0][r] + b;
            }
    }
    __syncthreads();

    // ---- log-prob epilogue: 4 rows per wave ----
    const float HALF_LOG2PI = 0.9189385332046727f;
    #pragma unroll
    for (int rr = 0; rr < 4; ++rr) {
        const int row = w * 4 + rr;
        const float shift = f[row * 128 + lane];
        const float ls    = f[row * 128 + 64 + lane];
        const float e     = enh[(row0 + row) * FEAT + lane];
        const float z = (e - shift) * __expf(-ls);
        float term = fmaf(-0.5f * z, z, -HALF_LOG2PI) - ls;
        #pragma unroll
        for (int b = 1; b < 64; b <<= 1) term += __shfl_xor(term, b, 64);
        if (lane == 0) out[row0 + row] = term;
    }
}

extern "C" void kernel_launch(void* const* d_in, const int* in_sizes, int n_in,
                              void* d_out, int out_size, void* d_ws, size_t ws_size,
                              hipStream_t stream) {
    const float* x     = (const float*)d_in[0];
    const float* theta = (const float*)d_in[1];
    const float* W_in  = (const float*)d_in[2];
    const float* b_in  = (const float*)d_in[3];
    const float* W_h   = (const float*)d_in[4];
    const float* b_h   = (const float*)d_in[5];
    const float* W_out = (const float*)d_in[6];
    const float* b_out = (const float*)d_in[7];
    float* out = (float*)d_out;

    float* enh = (float*)d_ws;                                    // 8 MB
    u16* wbuf = (u16*)((char*)d_ws + (size_t)N_SAMPLES * FEAT * 4);
    u16* win_hi  = wbuf;
    u16* win_lo  = win_hi + 32768;
    u16* wh_hi   = win_lo + 32768;
    u16* wh_lo   = wh_hi + 524288;
    u16* wout_hi = wh_lo + 524288;
    u16* wout_lo = wout_hi + 65536;

    qkernel<<<dim3(N_SAMPLES / 4), dim3(256), 0, stream>>>(x, theta, enh);
    prep<<<dim3(2432), dim3(256), 0, stream>>>(W_in, W_h, W_out,
        win_hi, win_lo, wh_hi, wh_lo, wout_hi, wout_lo);
    mlpkernel<<<dim3(N_SAMPLES / 32), dim3(512), 0, stream>>>(
        enh, win_hi, win_lo, b_in, wh_hi, wh_lo, b_h, wout_hi, wout_lo, b_out, out);
}

// Round 10
// 438.339 us; speedup vs baseline: 1.3649x; 1.3649x over previous
//
#include <hip/hip_runtime.h>
#include <hip/hip_bf16.h>
#include <math.h>

// ---------------------------------------------------------------------------
// QuantumEnhancedFlow — round 9 resubmit (round-9 bench was an infra failure)
//   qkernel : unchanged (product-state init + packed-f32 + ds_swizzle).
//   prep    : unchanged (split fp32 W -> hi/lo bf16).
//   mlpkernel: M-tile 64 rows/block (was 32). Per k-pair: 96 MFMAs (~480cy)
//             cover the 16 W-loads' L2 latency (~300cy) -- r7's 24 MFMAs
//             (~120cy) could not. LDS 128KB, 512thr/8 waves, NT=4, MT=4,
//             P/Q W dbuf, waves_per_eu(2,2) (the only proven no-spill budget).
// ws layout: [0,8MB) enh fp32 ; [8MB,10.5MB) W hi/lo bf16
// ---------------------------------------------------------------------------

#define N_SAMPLES 32768
#define FEAT 64

typedef unsigned short u16;
typedef __attribute__((ext_vector_type(2))) float f32x2;
typedef __attribute__((ext_vector_type(8))) short bf16x8_t;
typedef __attribute__((ext_vector_type(4))) float f32x4_t;

__device__ __forceinline__ u16 f2bf(float v) {
    __hip_bfloat16 b = __float2bfloat16(v);
    return __builtin_bit_cast(u16, b);
}
__device__ __forceinline__ float bf2f(u16 u) {
    return __bfloat162float(__builtin_bit_cast(__hip_bfloat16, u));
}

// ===========================================================================
// qkernel (unchanged)
// ===========================================================================
__device__ __forceinline__ f32x2 cmul(f32x2 a, f32x2 b) {
    f32x2 r = (f32x2){a.x, a.x} * b;
    f32x2 bs = __builtin_shufflevector(b, b, 1, 0);
    r = (f32x2){-a.y, a.y} * bs + r;
    return r;
}
template<int M>
__device__ __forceinline__ float xexf(float v) {
    if constexpr (M < 32) {
        constexpr int pat = (M << 10) | 0x1f;
        return __uint_as_float(__builtin_amdgcn_ds_swizzle(__float_as_uint(v), pat));
    } else {
        return __shfl_xor(v, 32, 64);
    }
}
template<int M>
__device__ __forceinline__ f32x2 xex2(f32x2 v) {
    return (f32x2){xexf<M>(v.x), xexf<M>(v.y)};
}

template<int Q>
__device__ __forceinline__ void rot_gate(f32x2 (&amp)[16],
                                         f32x2 g00, f32x2 g01, f32x2 g10, f32x2 g11,
                                         int lane) {
    if constexpr (Q < 4) {
        #pragma unroll
        for (int t = 0; t < 16; ++t) {
            if ((t & (1 << Q)) == 0) {
                const int t1 = t | (1 << Q);
                f32x2 a = amp[t], b = amp[t1];
                amp[t]  = cmul(g00, a) + cmul(g01, b);
                amp[t1] = cmul(g10, a) + cmul(g11, b);
            }
        }
    } else {
        constexpr int xm = 1 << (Q - 4);
        const bool hi = (lane >> (Q - 4)) & 1;
        f32x2 ga = hi ? g11 : g00;
        f32x2 gb = hi ? g10 : g01;
        #pragma unroll
        for (int t = 0; t < 16; ++t) {
            f32x2 b = xex2<xm>(amp[t]);
            amp[t] = cmul(ga, amp[t]) + cmul(gb, b);
        }
    }
}

template<int C, int T>
__device__ __forceinline__ void cx_local(f32x2 (&amp)[16]) {
    #pragma unroll
    for (int t = 0; t < 16; ++t) {
        if (((t >> C) & 1) && !((t >> T) & 1)) {
            const int t1 = t | (1 << T);
            f32x2 tmp = amp[t]; amp[t] = amp[t1]; amp[t1] = tmp;
        }
    }
}
__device__ __forceinline__ void cx_3_4(f32x2 (&amp)[16]) {
    #pragma unroll
    for (int t = 0; t < 16; ++t)
        if ((t >> 3) & 1) amp[t] = xex2<1>(amp[t]);
}
template<int CL, int TL>
__device__ __forceinline__ void cx_lane(f32x2 (&amp)[16], int lane) {
    const bool ctrl = (lane >> CL) & 1;
    #pragma unroll
    for (int t = 0; t < 16; ++t) {
        f32x2 v = xex2<(1 << TL)>(amp[t]);
        if (ctrl) amp[t] = v;
    }
}
__device__ __forceinline__ void cx_9_0(f32x2 (&amp)[16], int lane) {
    const bool ctrl = (lane >> 5) & 1;
    #pragma unroll
    for (int t = 0; t < 16; t += 2) {
        f32x2 a = amp[t], b = amp[t + 1];
        amp[t]     = ctrl ? b : a;
        amp[t + 1] = ctrl ? a : b;
    }
}

__global__ __launch_bounds__(256)
void qkernel(const float* __restrict__ x, const float* __restrict__ theta,
             float* __restrict__ enh) {
    __shared__ f32x2 gbuf[20][4];
    const int tid = threadIdx.x;
    if (tid < 20) {
        const int base = tid * 3;
        float s1, c1, s2, c2, sz, cz;
        sincosf(0.5f * theta[base + 0], &s1, &c1);
        sincosf(0.5f * theta[base + 1], &s2, &c2);
        sincosf(0.5f * theta[base + 2], &sz, &cz);
        f32x2 m00 = (f32x2){ c2*c1,  s2*s1};
        f32x2 m01 = (f32x2){-s2*c1, -c2*s1};
        f32x2 m10 = (f32x2){ s2*c1, -c2*s1};
        f32x2 m11 = (f32x2){ c2*c1, -s2*s1};
        f32x2 e0 = (f32x2){cz, -sz}, e1 = (f32x2){cz, sz};
        gbuf[tid][0] = cmul(e0, m00);
        gbuf[tid][1] = cmul(e0, m01);
        gbuf[tid][2] = cmul(e1, m10);
        gbuf[tid][3] = cmul(e1, m11);
    }
    __syncthreads();

    const int lane = tid & 63;
    const int s = blockIdx.x * 4 + (tid >> 6);
    const float xr = x[s * FEAT + lane];

    const float inv = 1.0f / sqrtf(fmaf(xr, xr, 1.0f));
    const float cq = inv, sq = xr * inv;

    float csv[10], snv[10];
    #pragma unroll
    for (int i = 0; i < 10; ++i) {
        csv[i] = __shfl(cq, i, 64);
        snv[i] = __shfl(sq, i, 64);
    }

    float lf = ((lane >> 0) & 1) ? snv[4] : csv[4];
    lf *= ((lane >> 1) & 1) ? snv[5] : csv[5];
    lf *= ((lane >> 2) & 1) ? snv[6] : csv[6];
    lf *= ((lane >> 3) & 1) ? snv[7] : csv[7];
    lf *= ((lane >> 4) & 1) ? snv[8] : csv[8];
    lf *= ((lane >> 5) & 1) ? snv[9] : csv[9];
    float l01[4], l23[4];
    l01[0] = csv[0]*csv[1]; l01[1] = snv[0]*csv[1];
    l01[2] = csv[0]*snv[1]; l01[3] = snv[0]*snv[1];
    l23[0] = csv[2]*csv[3]; l23[1] = snv[2]*csv[3];
    l23[2] = csv[2]*snv[3]; l23[3] = snv[2]*snv[3];

    f32x2 amp[16];
    #pragma unroll
    for (int t = 0; t < 16; ++t)
        amp[t] = (f32x2){lf * l01[t & 3] * l23[(t >> 2) & 3], 0.f};

    #pragma unroll
    for (int l = 0; l < 2; ++l) {
        const f32x2* gl = &gbuf[l * 10][0];
        #define ROT(Q) rot_gate<Q>(amp, gl[Q*4+0], gl[Q*4+1], gl[Q*4+2], gl[Q*4+3], lane);
        ROT(0) ROT(1) ROT(2) ROT(3) ROT(4) ROT(5) ROT(6) ROT(7) ROT(8) ROT(9)
        #undef ROT
        cx_local<0,1>(amp); cx_local<1,2>(amp); cx_local<2,3>(amp);
        cx_3_4(amp);
        cx_lane<0,1>(amp, lane); cx_lane<1,2>(amp, lane); cx_lane<2,3>(amp, lane);
        cx_lane<3,4>(amp, lane); cx_lane<4,5>(amp, lane);
        cx_9_0(amp, lane);
    }

    float p[16];
    #pragma unroll
    for (int t = 0; t < 16; ++t) p[t] = amp[t].x*amp[t].x + amp[t].y*amp[t].y;
    float o[10];
    #pragma unroll
    for (int i = 0; i < 4; ++i) {
        float acc = 0.f;
        #pragma unroll
        for (int t = 0; t < 16; ++t) acc += ((t >> i) & 1) ? -p[t] : p[t];
        o[i] = acc;
    }
    float ptot = 0.f;
    #pragma unroll
    for (int t = 0; t < 16; ++t) ptot += p[t];
    #pragma unroll
    for (int i = 4; i < 10; ++i) o[i] = ((lane >> (i - 4)) & 1) ? -ptot : ptot;
    #pragma unroll
    for (int i = 0; i < 10; ++i) {
        #pragma unroll
        for (int b = 1; b < 64; b <<= 1) o[i] += __shfl_xor(o[i], b, 64);
    }
    float outv = xr;
    #pragma unroll
    for (int i = 0; i < 10; ++i) if (lane == i) outv = o[i];
    enh[s * FEAT + lane] = outv;
}

// ===========================================================================
// prep (unchanged)
// ===========================================================================
__global__ __launch_bounds__(256)
void prep(const float* __restrict__ W_in, const float* __restrict__ W_h,
          const float* __restrict__ W_out,
          u16* __restrict__ win_hi, u16* __restrict__ win_lo,
          u16* __restrict__ wh_hi,  u16* __restrict__ wh_lo,
          u16* __restrict__ wout_hi,u16* __restrict__ wout_lo) {
    const int i = blockIdx.x * 256 + threadIdx.x;
    float v; u16 *ph, *pl; int off;
    if (i < 32768)        { v = W_in[i];          ph = win_hi;  pl = win_lo;  off = i; }
    else if (i < 557056)  { off = i - 32768;  v = W_h[off];   ph = wh_hi;   pl = wh_lo;  }
    else                  { off = i - 557056; v = W_out[off]; ph = wout_hi; pl = wout_lo; }
    const u16 hi = f2bf(v);
    const u16 lo = f2bf(v - bf2f(hi));
    ph[off] = hi; pl[off] = lo;
}

// ===========================================================================
// MFMA MLP — 64-row tile, 8 waves, MT=4 x NT per wave, P/Q W double-buffer
//   LDS h hi/lo [64][512] bf16 (128 KB), XOR-swizzled:
//     (m,k) stored at m*K + ((k>>3)^(m&7))*8 + (k&7)
// ===========================================================================
__device__ __forceinline__ float fast_tanh(float x) {
    const float e = __expf(2.0f * x);
    return 1.0f - 2.0f * __builtin_amdgcn_rcpf(e + 1.0f);
}

#define MT 4   // 4 m-tiles of 16 = 64 rows

template<int K, int NT>
__device__ __forceinline__ void gemm_frag(
        const u16* __restrict__ Whi, const u16* __restrict__ Wlo,
        const u16* hHi, const u16* hLo, int lane, int colbase,
        f32x4_t (&acc)[MT][NT]) {
    constexpr int KS = K / 32;
    const int l15 = lane & 15, l4 = lane >> 4, l7 = lane & 7;

    #pragma unroll
    for (int mt = 0; mt < MT; ++mt)
        #pragma unroll
        for (int nt = 0; nt < NT; ++nt) acc[mt][nt] = (f32x4_t)0.f;

    int woff[NT];
    #pragma unroll
    for (int nt = 0; nt < NT; ++nt)
        woff[nt] = (colbase + nt * 16 + l15) * K + l4 * 8;

    bf16x8_t pH[NT], pL[NT], qH[NT], qL[NT];
    #pragma unroll
    for (int nt = 0; nt < NT; ++nt) {
        pH[nt] = *(const bf16x8_t*)&Whi[woff[nt]];
        pL[nt] = *(const bf16x8_t*)&Wlo[woff[nt]];
        qH[nt] = *(const bf16x8_t*)&Whi[woff[nt] + 32];
        qL[nt] = *(const bf16x8_t*)&Wlo[woff[nt] + 32];
    }

    int ks = 0;
    #pragma unroll 1
    for (; ks + 2 < KS; ks += 2) {
        // ---- compute ks with P ----
        {
            bf16x8_t aH[MT], aL[MT];
            #pragma unroll
            for (int mt = 0; mt < MT; ++mt) {
                const int m = mt * 16 + l15;
                const int off = m * K + (((ks * 4 + l4) ^ (m & 7)) * 8);
                aH[mt] = *(const bf16x8_t*)&hHi[off];
                aL[mt] = *(const bf16x8_t*)&hLo[off];
            }
            #pragma unroll
            for (int nt = 0; nt < NT; ++nt)
                #pragma unroll
                for (int mt = 0; mt < MT; ++mt) {
                    acc[mt][nt] = __builtin_amdgcn_mfma_f32_16x16x32_bf16(aH[mt], pH[nt], acc[mt][nt], 0, 0, 0);
                    acc[mt][nt] = __builtin_amdgcn_mfma_f32_16x16x32_bf16(aH[mt], pL[nt], acc[mt][nt], 0, 0, 0);
                    acc[mt][nt] = __builtin_amdgcn_mfma_f32_16x16x32_bf16(aL[mt], pH[nt], acc[mt][nt], 0, 0, 0);
                }
        }
        // ---- prefetch P <- ks+2 ----
        #pragma unroll
        for (int nt = 0; nt < NT; ++nt) {
            pH[nt] = *(const bf16x8_t*)&Whi[woff[nt] + (ks + 2) * 32];
            pL[nt] = *(const bf16x8_t*)&Wlo[woff[nt] + (ks + 2) * 32];
        }
        // ---- compute ks+1 with Q ----
        {
            bf16x8_t aH[MT], aL[MT];
            #pragma unroll
            for (int mt = 0; mt < MT; ++mt) {
                const int m = mt * 16 + l15;
                const int off = m * K + ((((ks + 1) * 4 + l4) ^ (m & 7)) * 8);
                aH[mt] = *(const bf16x8_t*)&hHi[off];
                aL[mt] = *(const bf16x8_t*)&hLo[off];
            }
            #pragma unroll
            for (int nt = 0; nt < NT; ++nt)
                #pragma unroll
                for (int mt = 0; mt < MT; ++mt) {
                    acc[mt][nt] = __builtin_amdgcn_mfma_f32_16x16x32_bf16(aH[mt], qH[nt], acc[mt][nt], 0, 0, 0);
                    acc[mt][nt] = __builtin_amdgcn_mfma_f32_16x16x32_bf16(aH[mt], qL[nt], acc[mt][nt], 0, 0, 0);
                    acc[mt][nt] = __builtin_amdgcn_mfma_f32_16x16x32_bf16(aL[mt], qH[nt], acc[mt][nt], 0, 0, 0);
                }
        }
        // ---- prefetch Q <- ks+3 ----
        #pragma unroll
        for (int nt = 0; nt < NT; ++nt) {
            qH[nt] = *(const bf16x8_t*)&Whi[woff[nt] + (ks + 3) * 32];
            qL[nt] = *(const bf16x8_t*)&Wlo[woff[nt] + (ks + 3) * 32];
        }
    }
    // ---- epilogue pair ----
    {
        bf16x8_t aH[MT], aL[MT];
        #pragma unroll
        for (int mt = 0; mt < MT; ++mt) {
            const int m = mt * 16 + l15;
            const int off = m * K + (((ks * 4 + l4) ^ (m & 7)) * 8);
            aH[mt] = *(const bf16x8_t*)&hHi[off];
            aL[mt] = *(const bf16x8_t*)&hLo[off];
        }
        #pragma unroll
        for (int nt = 0; nt < NT; ++nt)
            #pragma unroll
            for (int mt = 0; mt < MT; ++mt) {
                acc[mt][nt] = __builtin_amdgcn_mfma_f32_16x16x32_bf16(aH[mt], pH[nt], acc[mt][nt], 0, 0, 0);
                acc[mt][nt] = __builtin_amdgcn_mfma_f32_16x16x32_bf16(aH[mt], pL[nt], acc[mt][nt], 0, 0, 0);
                acc[mt][nt] = __builtin_amdgcn_mfma_f32_16x16x32_bf16(aL[mt], pH[nt], acc[mt][nt], 0, 0, 0);
            }
        #pragma unroll
        for (int mt = 0; mt < MT; ++mt) {
            const int m = mt * 16 + l15;
            const int off = m * K + ((((ks + 1) * 4 + l4) ^ (m & 7)) * 8);
            aH[mt] = *(const bf16x8_t*)&hHi[off];
            aL[mt] = *(const bf16x8_t*)&hLo[off];
        }
        #pragma unroll
        for (int nt = 0; nt < NT; ++nt)
            #pragma unroll
            for (int mt = 0; mt < MT; ++mt) {
                acc[mt][nt] = __builtin_amdgcn_mfma_f32_16x16x32_bf16(aH[mt], qH[nt], acc[mt][nt], 0, 0, 0);
                acc[mt][nt] = __builtin_amdgcn_mfma_f32_16x16x32_bf16(aH[mt], qL[nt], acc[mt][nt], 0, 0, 0);
                acc[mt][nt] = __builtin_amdgcn_mfma_f32_16x16x32_bf16(aL[mt], qH[nt], acc[mt][nt], 0, 0, 0);
            }
    }
}

template<int NT>
__device__ __forceinline__ void write_h(
        f32x4_t (&acc)[MT][NT], const float* __restrict__ bias,
        u16* hHi, u16* hLo, int lane, int colbase) {
    const int l15 = lane & 15, l4 = lane >> 4;
    #pragma unroll
    for (int nt = 0; nt < NT; ++nt) {
        const int n = colbase + nt * 16 + l15;
        const float b = bias[n];
        #pragma unroll
        for (int mt = 0; mt < MT; ++mt)
            #pragma unroll
            for (int r = 0; r < 4; ++r) {
                const int m = mt * 16 + l4 * 4 + r;
                const float v = fast_tanh(acc[mt][nt][r] + b);
                const u16 hi = f2bf(v);
                const u16 lo = f2bf(v - bf2f(hi));
                const int blk = (n >> 3) ^ (m & 7);
                const int off = m * 512 + blk * 8 + (n & 7);
                hHi[off] = hi; hLo[off] = lo;
            }
    }
}

__global__ __attribute__((amdgpu_waves_per_eu(2, 2))) __launch_bounds__(512)
void mlpkernel(const float* __restrict__ enh,
               const u16* __restrict__ win_hi, const u16* __restrict__ win_lo,
               const float* __restrict__ b_in,
               const u16* __restrict__ wh_hi,  const u16* __restrict__ wh_lo,
               const float* __restrict__ b_h,
               const u16* __restrict__ wout_hi,const u16* __restrict__ wout_lo,
               const float* __restrict__ b_out,
               float* __restrict__ out) {
    __shared__ u16 hHi[64 * 512];           // 64 KB
    __shared__ u16 hLo[64 * 512];           // 64 KB
    const int tid = threadIdx.x;
    const int lane = tid & 63, w = tid >> 6;      // 8 waves
    const int row0 = blockIdx.x * 64;

    // ---- stage enhanced[64][64] -> LDS hi/lo (K=64 layout, swizzled) ----
    {
        const int r = tid >> 3, c0 = (tid & 7) * 8;   // 512 thr * 8 floats
        const float4 v0 = *(const float4*)&enh[(row0 + r) * FEAT + c0];
        const float4 v1 = *(const float4*)&enh[(row0 + r) * FEAT + c0 + 4];
        const float vv[8] = {v0.x, v0.y, v0.z, v0.w, v1.x, v1.y, v1.z, v1.w};
        bf16x8_t vh, vl;
        #pragma unroll
        for (int j = 0; j < 8; ++j) {
            const u16 hi = f2bf(vv[j]);
            const u16 lo = f2bf(vv[j] - bf2f(hi));
            vh[j] = (short)hi; vl[j] = (short)lo;
        }
        const int off = r * 64 + (((c0 >> 3) ^ (r & 7)) * 8);
        *(bf16x8_t*)&hHi[off] = vh;
        *(bf16x8_t*)&hLo[off] = vl;
    }
    __syncthreads();

    f32x4_t acc[MT][4];
    gemm_frag<64, 4>(win_hi, win_lo, hHi, hLo, lane, w * 64, acc);
    __syncthreads();
    write_h<4>(acc, b_in, hHi, hLo, lane, w * 64);
    __syncthreads();
    gemm_frag<512, 4>(wh_hi, wh_lo, hHi, hLo, lane, w * 64, acc);
    __syncthreads();
    write_h<4>(acc, b_h, hHi, hLo, lane, w * 64);
    __syncthreads();
    gemm_frag<512, 4>(wh_hi + 262144, wh_lo + 262144, hHi, hLo, lane, w * 64, acc);
    __syncthreads();
    write_h<4>(acc, b_h + 512, hHi, hLo, lane, w * 64);
    __syncthreads();
    f32x4_t acc2[MT][1];
    gemm_frag<512, 1>(wout_hi, wout_lo, hHi, hLo, lane, w * 16, acc2);
    __syncthreads();

    float* f = (float*)hHi;     // reuse LDS: out tile [64][128] fp32 (32 KB)
    {
        const int l15 = lane & 15, l4 = lane >> 4;
        const int n = w * 16 + l15;
        const float b = b_out[n];
        #pragma unroll
        for (int mt = 0; mt < MT; ++mt)
            #pragma unroll
            for (int r = 0; r < 4; ++r) {
                const int m = mt * 16 + l4 * 4 + r;
                f[m * 128 + n] = acc2[mt][0][r] + b;
            }
    }
    __syncthreads();

    // ---- log-prob epilogue: 8 rows per wave ----
    const float HALF_LOG2PI = 0.9189385332046727f;
    #pragma unroll
    for (int rr = 0; rr < 8; ++rr) {
        const int row = w * 8 + rr;
        const float shift = f[row * 128 + lane];
        const float ls    = f[row * 128 + 64 + lane];
        const float e     = enh[(row0 + row) * FEAT + lane];
        const float z = (e - shift) * __expf(-ls);
        float term = fmaf(-0.5f * z, z, -HALF_LOG2PI) - ls;
        #pragma unroll
        for (int b = 1; b < 64; b <<= 1) term += __shfl_xor(term, b, 64);
        if (lane == 0) out[row0 + row] = term;
    }
}

extern "C" void kernel_launch(void* const* d_in, const int* in_sizes, int n_in,
                              void* d_out, int out_size, void* d_ws, size_t ws_size,
                              hipStream_t stream) {
    const float* x     = (const float*)d_in[0];
    const float* theta = (const float*)d_in[1];
    const float* W_in  = (const float*)d_in[2];
    const float* b_in  = (const float*)d_in[3];
    const float* W_h   = (const float*)d_in[4];
    const float* b_h   = (const float*)d_in[5];
    const float* W_out = (const float*)d_in[6];
    const float* b_out = (const float*)d_in[7];
    float* out = (float*)d_out;

    float* enh = (float*)d_ws;                                    // 8 MB
    u16* wbuf = (u16*)((char*)d_ws + (size_t)N_SAMPLES * FEAT * 4);
    u16* win_hi  = wbuf;
    u16* win_lo  = win_hi + 32768;
    u16* wh_hi   = win_lo + 32768;
    u16* wh_lo   = wh_hi + 524288;
    u16* wout_hi = wh_lo + 524288;
    u16* wout_lo = wout_hi + 65536;

    qkernel<<<dim3(N_SAMPLES / 4), dim3(256), 0, stream>>>(x, theta, enh);
    prep<<<dim3(2432), dim3(256), 0, stream>>>(W_in, W_h, W_out,
        win_hi, win_lo, wh_hi, wh_lo, wout_hi, wout_lo);
    mlpkernel<<<dim3(N_SAMPLES / 64), dim3(512), 0, stream>>>(
        enh, win_hi, win_lo, b_in, wh_hi, wh_lo, b_h, wout_hi, wout_lo, b_out, out);
}

// Round 11
// 427.049 us; speedup vs baseline: 1.4010x; 1.0264x over previous
//
#include <hip/hip_runtime.h>
#include <hip/hip_bf16.h>
#include <math.h>

// ---------------------------------------------------------------------------
// QuantumEnhancedFlow — round 11
//   qprep  : statevector sim with CX networks ELIMINATED algebraically:
//            CX perm P is linear over GF(2) (index map F). Layer-2 gates act
//            along D_q = F e_q with role parity R_q = row_q(F^-1); both perms
//            fold into measurement sign masks t_i = row_i(F^-2). prep (W
//            split) fused into the same launch as extra blocks.
//   mlpkernel: MT=4 split-bf16 MFMA MLP; waves_per_eu(1,2) to unlock the
//            256-VGPR budget (empirical: budget = 256/min_waves; (2,2) capped
//            at 128 and spilled 36 MB in r10).
// ws layout: [0,8MB) enh fp32 ; [8MB,10.5MB) W hi/lo bf16
// ---------------------------------------------------------------------------

#define N_SAMPLES 32768
#define FEAT 64
#define QBLOCKS (N_SAMPLES / 4)      // 8192
#define PREPBLOCKS 2432              // 622592 / 256

typedef unsigned short u16;
typedef __attribute__((ext_vector_type(2))) float f32x2;
typedef __attribute__((ext_vector_type(8))) short bf16x8_t;
typedef __attribute__((ext_vector_type(4))) float f32x4_t;

__device__ __forceinline__ u16 f2bf(float v) {
    __hip_bfloat16 b = __float2bfloat16(v);
    return __builtin_bit_cast(u16, b);
}
__device__ __forceinline__ float bf2f(u16 u) {
    return __bfloat162float(__builtin_bit_cast(__hip_bfloat16, u));
}

// ===========================================================================
// quantum sim helpers
// ===========================================================================
__device__ __forceinline__ f32x2 cmul(f32x2 a, f32x2 b) {
    f32x2 r = (f32x2){a.x, a.x} * b;
    f32x2 bs = __builtin_shufflevector(b, b, 1, 0);
    r = (f32x2){-a.y, a.y} * bs + r;
    return r;
}
// lane exchange lane^M (M=0 passthrough; M<32 ds_swizzle; else shfl_xor)
template<int M>
__device__ __forceinline__ float xexf(float v) {
    if constexpr (M == 0) {
        return v;
    } else if constexpr (M < 32) {
        constexpr int pat = (M << 10) | 0x1f;   // BitMode xor=M, and=0x1f
        return __uint_as_float(__builtin_amdgcn_ds_swizzle(__float_as_uint(v), pat));
    } else {
        return __shfl_xor(v, M, 64);
    }
}
template<int M>
__device__ __forceinline__ f32x2 xex2(f32x2 v) {
    return (f32x2){xexf<M>(v.x), xexf<M>(v.y)};
}

// layer-1 gate on physical qubit Q (unchanged)
template<int Q>
__device__ __forceinline__ void rot_gate(f32x2 (&amp)[16],
                                         f32x2 g00, f32x2 g01, f32x2 g10, f32x2 g11,
                                         int lane) {
    if constexpr (Q < 4) {
        #pragma unroll
        for (int t = 0; t < 16; ++t) {
            if ((t & (1 << Q)) == 0) {
                const int t1 = t | (1 << Q);
                f32x2 a = amp[t], b = amp[t1];
                amp[t]  = cmul(g00, a) + cmul(g01, b);
                amp[t1] = cmul(g10, a) + cmul(g11, b);
            }
        }
    } else {
        constexpr int xm = 1 << (Q - 4);
        const bool hi = (lane >> (Q - 4)) & 1;
        f32x2 ga = hi ? g11 : g00;
        f32x2 gb = hi ? g10 : g01;
        #pragma unroll
        for (int t = 0; t < 16; ++t) {
            f32x2 b = xex2<xm>(amp[t]);
            amp[t] = cmul(ga, amp[t]) + cmul(gb, b);
        }
    }
}

// layer-2 gate conjugated through the CX network:
//   pairs (k, k^D); role(k) = parity(k & R); k = (lane<<4)|t
template<int D, int R>
__device__ __forceinline__ void rot2(f32x2 (&amp)[16],
                                     f32x2 g00, f32x2 g01, f32x2 g10, f32x2 g11,
                                     int lane) {
    constexpr int DL = D & 15;
    constexpr int DP = (D >> 4) & 63;
    constexpr int RL = R & 15;
    constexpr int RP = (R >> 4) & 63;
    const bool lp = __popc(lane & RP) & 1;
    const f32x2 gA0 = lp ? g11 : g00, gB0 = lp ? g10 : g01;   // for pt=0
    const f32x2 gA1 = lp ? g00 : g11, gB1 = lp ? g01 : g10;   // for pt=1
    f32x2 b[16];
    #pragma unroll
    for (int t = 0; t < 16; ++t) b[t] = xex2<DP>(amp[t ^ DL]);
    #pragma unroll
    for (int t = 0; t < 16; ++t) {
        const bool pt = __popc(t & RL) & 1;   // compile-time folded
        amp[t] = cmul(pt ? gA1 : gA0, amp[t]) + cmul(pt ? gB1 : gB0, b[t]);
    }
}

// ===========================================================================
// qprep: quantum sim blocks [0, QBLOCKS) + W-split blocks [QBLOCKS, +PREP)
// ===========================================================================
__global__ __launch_bounds__(256)
void qprep(const float* __restrict__ x, const float* __restrict__ theta,
           float* __restrict__ enh,
           const float* __restrict__ W_in, const float* __restrict__ W_h,
           const float* __restrict__ W_out,
           u16* __restrict__ win_hi, u16* __restrict__ win_lo,
           u16* __restrict__ wh_hi,  u16* __restrict__ wh_lo,
           u16* __restrict__ wout_hi,u16* __restrict__ wout_lo) {
    const int tid = threadIdx.x;
    const int bid = blockIdx.x;

    if (bid >= QBLOCKS) {                    // ---- prep branch ----
        const int i = (bid - QBLOCKS) * 256 + tid;
        float v; u16 *ph, *pl; int off;
        if (i < 32768)        { v = W_in[i];          ph = win_hi;  pl = win_lo;  off = i; }
        else if (i < 557056)  { off = i - 32768;  v = W_h[off];   ph = wh_hi;   pl = wh_lo;  }
        else                  { off = i - 557056; v = W_out[off]; ph = wout_hi; pl = wout_lo; }
        const u16 hi = f2bf(v);
        const u16 lo = f2bf(v - bf2f(hi));
        ph[off] = hi; pl[off] = lo;
        return;
    }

    __shared__ f32x2 gbuf[20][4];
    if (tid < 20) {
        const int base = tid * 3;
        float s1, c1, s2, c2, sz, cz;
        sincosf(0.5f * theta[base + 0], &s1, &c1);
        sincosf(0.5f * theta[base + 1], &s2, &c2);
        sincosf(0.5f * theta[base + 2], &sz, &cz);
        f32x2 m00 = (f32x2){ c2*c1,  s2*s1};
        f32x2 m01 = (f32x2){-s2*c1, -c2*s1};
        f32x2 m10 = (f32x2){ s2*c1, -c2*s1};
        f32x2 m11 = (f32x2){ c2*c1, -s2*s1};
        f32x2 e0 = (f32x2){cz, -sz}, e1 = (f32x2){cz, sz};
        gbuf[tid][0] = cmul(e0, m00);
        gbuf[tid][1] = cmul(e0, m01);
        gbuf[tid][2] = cmul(e1, m10);
        gbuf[tid][3] = cmul(e1, m11);
    }
    __syncthreads();

    const int lane = tid & 63;
    const int s = bid * 4 + (tid >> 6);
    const float xr = x[s * FEAT + lane];

    const float inv = 1.0f / sqrtf(fmaf(xr, xr, 1.0f));
    const float cq = inv, sq = xr * inv;

    float csv[10], snv[10];
    #pragma unroll
    for (int i = 0; i < 10; ++i) {
        csv[i] = __shfl(cq, i, 64);
        snv[i] = __shfl(sq, i, 64);
    }

    // product-state init
    float lf = ((lane >> 0) & 1) ? snv[4] : csv[4];
    lf *= ((lane >> 1) & 1) ? snv[5] : csv[5];
    lf *= ((lane >> 2) & 1) ? snv[6] : csv[6];
    lf *= ((lane >> 3) & 1) ? snv[7] : csv[7];
    lf *= ((lane >> 4) & 1) ? snv[8] : csv[8];
    lf *= ((lane >> 5) & 1) ? snv[9] : csv[9];
    float l01[4], l23[4];
    l01[0] = csv[0]*csv[1]; l01[1] = snv[0]*csv[1];
    l01[2] = csv[0]*snv[1]; l01[3] = snv[0]*snv[1];
    l23[0] = csv[2]*csv[3]; l23[1] = snv[2]*csv[3];
    l23[2] = csv[2]*snv[3]; l23[3] = snv[2]*snv[3];

    f32x2 amp[16];
    #pragma unroll
    for (int t = 0; t < 16; ++t)
        amp[t] = (f32x2){lf * l01[t & 3] * l23[(t >> 2) & 3], 0.f};

    // ---- layer 1: physical-qubit gates (CX folded forward) ----
    {
        const f32x2* g1 = &gbuf[0][0];
        #define ROT(Q) rot_gate<Q>(amp, g1[Q*4+0], g1[Q*4+1], g1[Q*4+2], g1[Q*4+3], lane);
        ROT(0) ROT(1) ROT(2) ROT(3) ROT(4) ROT(5) ROT(6) ROT(7) ROT(8) ROT(9)
        #undef ROT
    }
    // ---- layer 2: CX-conjugated gates. D_q = F e_q, R_q = row_q(F^-1) ----
    {
        const f32x2* g2 = &gbuf[10][0];
        #define ROT2(Q, D, R) rot2<D, R>(amp, g2[Q*4+0], g2[Q*4+1], g2[Q*4+2], g2[Q*4+3], lane);
        ROT2(0, 0x003, 0x3FE)
        ROT2(1, 0x006, 0x003)
        ROT2(2, 0x00C, 0x007)
        ROT2(3, 0x018, 0x00F)
        ROT2(4, 0x030, 0x01F)
        ROT2(5, 0x060, 0x03F)
        ROT2(6, 0x0C0, 0x07F)
        ROT2(7, 0x180, 0x0FF)
        ROT2(8, 0x300, 0x1FF)
        ROT2(9, 0x203, 0x3FF)
        #undef ROT2
    }

    // ---- expectations: <Z_i> with sign masks t_i = row_i(F^-2) ----
    float p[16];
    #pragma unroll
    for (int t = 0; t < 16; ++t) p[t] = amp[t].x*amp[t].x + amp[t].y*amp[t].y;

    float S5 = 0.f, SA = 0.f, SB = 0.f, SD = 0.f;
    #pragma unroll
    for (int t = 0; t < 16; ++t) {
        S5 += (__popc(t & 0x5) & 1) ? -p[t] : p[t];
        SA += (__popc(t & 0xA) & 1) ? -p[t] : p[t];
        SB += (__popc(t & 0xB) & 1) ? -p[t] : p[t];
        SD += (__popc(t & 0xD) & 1) ? -p[t] : p[t];
    }
    // t_i: local mask selects the sum, lane mask flips sign
    float o[10];
    o[0] = SB; o[1] = SD; o[2] = SA; o[3] = S5; o[4] = SA;
    o[5] = S5; o[6] = SA; o[7] = S5; o[8] = SA; o[9] = S5;
    if (__popc(lane & 0x2A) & 1) o[0] = -o[0];
    if (__popc(lane & 0x3F) & 1) o[1] = -o[1];
    if (__popc(lane & 0x3F) & 1) o[2] = -o[2];
    if (__popc(lane & 0x3F) & 1) o[3] = -o[3];
    if (__popc(lane & 0x3E) & 1) o[4] = -o[4];
    if (__popc(lane & 0x3D) & 1) o[5] = -o[5];
    if (__popc(lane & 0x3A) & 1) o[6] = -o[6];
    if (__popc(lane & 0x35) & 1) o[7] = -o[7];
    if (__popc(lane & 0x2A) & 1) o[8] = -o[8];
    if (__popc(lane & 0x15) & 1) o[9] = -o[9];

    #pragma unroll
    for (int i = 0; i < 10; ++i) {
        #pragma unroll
        for (int b = 1; b < 64; b <<= 1) o[i] += __shfl_xor(o[i], b, 64);
    }
    float outv = xr;
    #pragma unroll
    for (int i = 0; i < 10; ++i) if (lane == i) outv = o[i];
    enh[s * FEAT + lane] = outv;
}

// ===========================================================================
// MFMA MLP — 64-row tile, 8 waves, MT=4 x NT per wave, P/Q W double-buffer
//   LDS h hi/lo [64][512] bf16 (128 KB), XOR-swizzled:
//     (m,k) stored at m*K + ((k>>3)^(m&7))*8 + (k&7)
// ===========================================================================
__device__ __forceinline__ float fast_tanh(float x) {
    const float e = __expf(2.0f * x);
    return 1.0f - 2.0f * __builtin_amdgcn_rcpf(e + 1.0f);
}

#define MT 4   // 4 m-tiles of 16 = 64 rows

template<int K, int NT>
__device__ __forceinline__ void gemm_frag(
        const u16* __restrict__ Whi, const u16* __restrict__ Wlo,
        const u16* hHi, const u16* hLo, int lane, int colbase,
        f32x4_t (&acc)[MT][NT]) {
    constexpr int KS = K / 32;
    const int l15 = lane & 15, l4 = lane >> 4, l7 = lane & 7;

    #pragma unroll
    for (int mt = 0; mt < MT; ++mt)
        #pragma unroll
        for (int nt = 0; nt < NT; ++nt) acc[mt][nt] = (f32x4_t)0.f;

    int woff[NT];
    #pragma unroll
    for (int nt = 0; nt < NT; ++nt)
        woff[nt] = (colbase + nt * 16 + l15) * K + l4 * 8;

    bf16x8_t pH[NT], pL[NT], qH[NT], qL[NT];
    #pragma unroll
    for (int nt = 0; nt < NT; ++nt) {
        pH[nt] = *(const bf16x8_t*)&Whi[woff[nt]];
        pL[nt] = *(const bf16x8_t*)&Wlo[woff[nt]];
        qH[nt] = *(const bf16x8_t*)&Whi[woff[nt] + 32];
        qL[nt] = *(const bf16x8_t*)&Wlo[woff[nt] + 32];
    }

    int ks = 0;
    #pragma unroll 1
    for (; ks + 2 < KS; ks += 2) {
        {
            bf16x8_t aH[MT], aL[MT];
            #pragma unroll
            for (int mt = 0; mt < MT; ++mt) {
                const int m = mt * 16 + l15;
                const int off = m * K + (((ks * 4 + l4) ^ (m & 7)) * 8);
                aH[mt] = *(const bf16x8_t*)&hHi[off];
                aL[mt] = *(const bf16x8_t*)&hLo[off];
            }
            #pragma unroll
            for (int nt = 0; nt < NT; ++nt)
                #pragma unroll
                for (int mt = 0; mt < MT; ++mt) {
                    acc[mt][nt] = __builtin_amdgcn_mfma_f32_16x16x32_bf16(aH[mt], pH[nt], acc[mt][nt], 0, 0, 0);
                    acc[mt][nt] = __builtin_amdgcn_mfma_f32_16x16x32_bf16(aH[mt], pL[nt], acc[mt][nt], 0, 0, 0);
                    acc[mt][nt] = __builtin_amdgcn_mfma_f32_16x16x32_bf16(aL[mt], pH[nt], acc[mt][nt], 0, 0, 0);
                }
        }
        #pragma unroll
        for (int nt = 0; nt < NT; ++nt) {
            pH[nt] = *(const bf16x8_t*)&Whi[woff[nt] + (ks + 2) * 32];
            pL[nt] = *(const bf16x8_t*)&Wlo[woff[nt] + (ks + 2) * 32];
        }
        {
            bf16x8_t aH[MT], aL[MT];
            #pragma unroll
            for (int mt = 0; mt < MT; ++mt) {
                const int m = mt * 16 + l15;
                const int off = m * K + ((((ks + 1) * 4 + l4) ^ (m & 7)) * 8);
                aH[mt] = *(const bf16x8_t*)&hHi[off];
                aL[mt] = *(const bf16x8_t*)&hLo[off];
            }
            #pragma unroll
            for (int nt = 0; nt < NT; ++nt)
                #pragma unroll
                for (int mt = 0; mt < MT; ++mt) {
                    acc[mt][nt] = __builtin_amdgcn_mfma_f32_16x16x32_bf16(aH[mt], qH[nt], acc[mt][nt], 0, 0, 0);
                    acc[mt][nt] = __builtin_amdgcn_mfma_f32_16x16x32_bf16(aH[mt], qL[nt], acc[mt][nt], 0, 0, 0);
                    acc[mt][nt] = __builtin_amdgcn_mfma_f32_16x16x32_bf16(aL[mt], qH[nt], acc[mt][nt], 0, 0, 0);
                }
        }
        #pragma unroll
        for (int nt = 0; nt < NT; ++nt) {
            qH[nt] = *(const bf16x8_t*)&Whi[woff[nt] + (ks + 3) * 32];
            qL[nt] = *(const bf16x8_t*)&Wlo[woff[nt] + (ks + 3) * 32];
        }
    }
    {
        bf16x8_t aH[MT], aL[MT];
        #pragma unroll
        for (int mt = 0; mt < MT; ++mt) {
            const int m = mt * 16 + l15;
            const int off = m * K + (((ks * 4 + l4) ^ (m & 7)) * 8);
            aH[mt] = *(const bf16x8_t*)&hHi[off];
            aL[mt] = *(const bf16x8_t*)&hLo[off];
        }
        #pragma unroll
        for (int nt = 0; nt < NT; ++nt)
            #pragma unroll
            for (int mt = 0; mt < MT; ++mt) {
                acc[mt][nt] = __builtin_amdgcn_mfma_f32_16x16x32_bf16(aH[mt], pH[nt], acc[mt][nt], 0, 0, 0);
                acc[mt][nt] = __builtin_amdgcn_mfma_f32_16x16x32_bf16(aH[mt], pL[nt], acc[mt][nt], 0, 0, 0);
                acc[mt][nt] = __builtin_amdgcn_mfma_f32_16x16x32_bf16(aL[mt], pH[nt], acc[mt][nt], 0, 0, 0);
            }
        #pragma unroll
        for (int mt = 0; mt < MT; ++mt) {
            const int m = mt * 16 + l15;
            const int off = m * K + ((((ks + 1) * 4 + l4) ^ (m & 7)) * 8);
            aH[mt] = *(const bf16x8_t*)&hHi[off];
            aL[mt] = *(const bf16x8_t*)&hLo[off];
        }
        #pragma unroll
        for (int nt = 0; nt < NT; ++nt)
            #pragma unroll
            for (int mt = 0; mt < MT; ++mt) {
                acc[mt][nt] = __builtin_amdgcn_mfma_f32_16x16x32_bf16(aH[mt], qH[nt], acc[mt][nt], 0, 0, 0);
                acc[mt][nt] = __builtin_amdgcn_mfma_f32_16x16x32_bf16(aH[mt], qL[nt], acc[mt][nt], 0, 0, 0);
                acc[mt][nt] = __builtin_amdgcn_mfma_f32_16x16x32_bf16(aL[mt], qH[nt], acc[mt][nt], 0, 0, 0);
            }
    }
}

template<int NT>
__device__ __forceinline__ void write_h(
        f32x4_t (&acc)[MT][NT], const float* __restrict__ bias,
        u16* hHi, u16* hLo, int lane, int colbase) {
    const int l15 = lane & 15, l4 = lane >> 4;
    #pragma unroll
    for (int nt = 0; nt < NT; ++nt) {
        const int n = colbase + nt * 16 + l15;
        const float b = bias[n];
        #pragma unroll
        for (int mt = 0; mt < MT; ++mt)
            #pragma unroll
            for (int r = 0; r < 4; ++r) {
                const int m = mt * 16 + l4 * 4 + r;
                const float v = fast_tanh(acc[mt][nt][r] + b);
                const u16 hi = f2bf(v);
                const u16 lo = f2bf(v - bf2f(hi));
                const int blk = (n >> 3) ^ (m & 7);
                const int off = m * 512 + blk * 8 + (n & 7);
                hHi[off] = hi; hLo[off] = lo;
            }
    }
}

__global__ __attribute__((amdgpu_waves_per_eu(1, 2))) __launch_bounds__(512)
void mlpkernel(const float* __restrict__ enh,
               const u16* __restrict__ win_hi, const u16* __restrict__ win_lo,
               const float* __restrict__ b_in,
               const u16* __restrict__ wh_hi,  const u16* __restrict__ wh_lo,
               const float* __restrict__ b_h,
               const u16* __restrict__ wout_hi,const u16* __restrict__ wout_lo,
               const float* __restrict__ b_out,
               float* __restrict__ out) {
    __shared__ u16 hHi[64 * 512];           // 64 KB
    __shared__ u16 hLo[64 * 512];           // 64 KB
    const int tid = threadIdx.x;
    const int lane = tid & 63, w = tid >> 6;      // 8 waves
    const int row0 = blockIdx.x * 64;

    {
        const int r = tid >> 3, c0 = (tid & 7) * 8;
        const float4 v0 = *(const float4*)&enh[(row0 + r) * FEAT + c0];
        const float4 v1 = *(const float4*)&enh[(row0 + r) * FEAT + c0 + 4];
        const float vv[8] = {v0.x, v0.y, v0.z, v0.w, v1.x, v1.y, v1.z, v1.w};
        bf16x8_t vh, vl;
        #pragma unroll
        for (int j = 0; j < 8; ++j) {
            const u16 hi = f2bf(vv[j]);
            const u16 lo = f2bf(vv[j] - bf2f(hi));
            vh[j] = (short)hi; vl[j] = (short)lo;
        }
        const int off = r * 64 + (((c0 >> 3) ^ (r & 7)) * 8);
        *(bf16x8_t*)&hHi[off] = vh;
        *(bf16x8_t*)&hLo[off] = vl;
    }
    __syncthreads();

    f32x4_t acc[MT][4];
    gemm_frag<64, 4>(win_hi, win_lo, hHi, hLo, lane, w * 64, acc);
    __syncthreads();
    write_h<4>(acc, b_in, hHi, hLo, lane, w * 64);
    __syncthreads();
    gemm_frag<512, 4>(wh_hi, wh_lo, hHi, hLo, lane, w * 64, acc);
    __syncthreads();
    write_h<4>(acc, b_h, hHi, hLo, lane, w * 64);
    __syncthreads();
    gemm_frag<512, 4>(wh_hi + 262144, wh_lo + 262144, hHi, hLo, lane, w * 64, acc);
    __syncthreads();
    write_h<4>(acc, b_h + 512, hHi, hLo, lane, w * 64);
    __syncthreads();
    f32x4_t acc2[MT][1];
    gemm_frag<512, 1>(wout_hi, wout_lo, hHi, hLo, lane, w * 16, acc2);
    __syncthreads();

    float* f = (float*)hHi;     // reuse LDS: out tile [64][128] fp32 (32 KB)
    {
        const int l15 = lane & 15, l4 = lane >> 4;
        const int n = w * 16 + l15;
        const float b = b_out[n];
        #pragma unroll
        for (int mt = 0; mt < MT; ++mt)
            #pragma unroll
            for (int r = 0; r < 4; ++r) {
                const int m = mt * 16 + l4 * 4 + r;
                f[m * 128 + n] = acc2[mt][0][r] + b;
            }
    }
    __syncthreads();

    const float HALF_LOG2PI = 0.9189385332046727f;
    #pragma unroll
    for (int rr = 0; rr < 8; ++rr) {
        const int row = w * 8 + rr;
        const float shift = f[row * 128 + lane];
        const float ls    = f[row * 128 + 64 + lane];
        const float e     = enh[(row0 + row) * FEAT + lane];
        const float z = (e - shift) * __expf(-ls);
        float term = fmaf(-0.5f * z, z, -HALF_LOG2PI) - ls;
        #pragma unroll
        for (int b = 1; b < 64; b <<= 1) term += __shfl_xor(term, b, 64);
        if (lane == 0) out[row0 + row] = term;
    }
}

extern "C" void kernel_launch(void* const* d_in, const int* in_sizes, int n_in,
                              void* d_out, int out_size, void* d_ws, size_t ws_size,
                              hipStream_t stream) {
    const float* x     = (const float*)d_in[0];
    const float* theta = (const float*)d_in[1];
    const float* W_in  = (const float*)d_in[2];
    const float* b_in  = (const float*)d_in[3];
    const float* W_h   = (const float*)d_in[4];
    const float* b_h   = (const float*)d_in[5];
    const float* W_out = (const float*)d_in[6];
    const float* b_out = (const float*)d_in[7];
    float* out = (float*)d_out;

    float* enh = (float*)d_ws;                                    // 8 MB
    u16* wbuf = (u16*)((char*)d_ws + (size_t)N_SAMPLES * FEAT * 4);
    u16* win_hi  = wbuf;
    u16* win_lo  = win_hi + 32768;
    u16* wh_hi   = win_lo + 32768;
    u16* wh_lo   = wh_hi + 524288;
    u16* wout_hi = wh_lo + 524288;
    u16* wout_lo = wout_hi + 65536;

    qprep<<<dim3(QBLOCKS + PREPBLOCKS), dim3(256), 0, stream>>>(
        x, theta, enh, W_in, W_h, W_out,
        win_hi, win_lo, wh_hi, wh_lo, wout_hi, wout_lo);
    mlpkernel<<<dim3(N_SAMPLES / 64), dim3(512), 0, stream>>>(
        enh, win_hi, win_lo, b_in, wh_hi, wh_lo, b_h, wout_hi, wout_lo, b_out, out);
}

// Round 12
// 425.304 us; speedup vs baseline: 1.4067x; 1.0041x over previous
//
#include <hip/hip_runtime.h>
#include <hip/hip_bf16.h>
#include <math.h>

// ---------------------------------------------------------------------------
// QuantumEnhancedFlow — round 12
//   qprep  : unchanged (CX-folded sim + fused W split).
//   mlpkernel: 1024 thr / 16 waves, NT=2 per wave (was 8 waves NT=4).
//            Per-wave reg demand ~115 <= the 128 cap the allocator enforces
//            at waves_per_eu(2,2) -> NO spill (r10/r11 spilled 36 MB), and
//            4 waves/SIMD runtime TLP (vs 2). Same 64x512 tile / MFMA count.
// ws layout: [0,8MB) enh fp32 ; [8MB,10.5MB) W hi/lo bf16
// ---------------------------------------------------------------------------

#define N_SAMPLES 32768
#define FEAT 64
#define QBLOCKS (N_SAMPLES / 4)      // 8192
#define PREPBLOCKS 2432              // 622592 / 256

typedef unsigned short u16;
typedef __attribute__((ext_vector_type(2))) float f32x2;
typedef __attribute__((ext_vector_type(8))) short bf16x8_t;
typedef __attribute__((ext_vector_type(4))) float f32x4_t;

__device__ __forceinline__ u16 f2bf(float v) {
    __hip_bfloat16 b = __float2bfloat16(v);
    return __builtin_bit_cast(u16, b);
}
__device__ __forceinline__ float bf2f(u16 u) {
    return __bfloat162float(__builtin_bit_cast(__hip_bfloat16, u));
}

// ===========================================================================
// quantum sim helpers (unchanged from r11)
// ===========================================================================
__device__ __forceinline__ f32x2 cmul(f32x2 a, f32x2 b) {
    f32x2 r = (f32x2){a.x, a.x} * b;
    f32x2 bs = __builtin_shufflevector(b, b, 1, 0);
    r = (f32x2){-a.y, a.y} * bs + r;
    return r;
}
template<int M>
__device__ __forceinline__ float xexf(float v) {
    if constexpr (M == 0) {
        return v;
    } else if constexpr (M < 32) {
        constexpr int pat = (M << 10) | 0x1f;
        return __uint_as_float(__builtin_amdgcn_ds_swizzle(__float_as_uint(v), pat));
    } else {
        return __shfl_xor(v, M, 64);
    }
}
template<int M>
__device__ __forceinline__ f32x2 xex2(f32x2 v) {
    return (f32x2){xexf<M>(v.x), xexf<M>(v.y)};
}

template<int Q>
__device__ __forceinline__ void rot_gate(f32x2 (&amp)[16],
                                         f32x2 g00, f32x2 g01, f32x2 g10, f32x2 g11,
                                         int lane) {
    if constexpr (Q < 4) {
        #pragma unroll
        for (int t = 0; t < 16; ++t) {
            if ((t & (1 << Q)) == 0) {
                const int t1 = t | (1 << Q);
                f32x2 a = amp[t], b = amp[t1];
                amp[t]  = cmul(g00, a) + cmul(g01, b);
                amp[t1] = cmul(g10, a) + cmul(g11, b);
            }
        }
    } else {
        constexpr int xm = 1 << (Q - 4);
        const bool hi = (lane >> (Q - 4)) & 1;
        f32x2 ga = hi ? g11 : g00;
        f32x2 gb = hi ? g10 : g01;
        #pragma unroll
        for (int t = 0; t < 16; ++t) {
            f32x2 b = xex2<xm>(amp[t]);
            amp[t] = cmul(ga, amp[t]) + cmul(gb, b);
        }
    }
}

template<int D, int R>
__device__ __forceinline__ void rot2(f32x2 (&amp)[16],
                                     f32x2 g00, f32x2 g01, f32x2 g10, f32x2 g11,
                                     int lane) {
    constexpr int DL = D & 15;
    constexpr int DP = (D >> 4) & 63;
    constexpr int RL = R & 15;
    constexpr int RP = (R >> 4) & 63;
    const bool lp = __popc(lane & RP) & 1;
    const f32x2 gA0 = lp ? g11 : g00, gB0 = lp ? g10 : g01;
    const f32x2 gA1 = lp ? g00 : g11, gB1 = lp ? g01 : g10;
    f32x2 b[16];
    #pragma unroll
    for (int t = 0; t < 16; ++t) b[t] = xex2<DP>(amp[t ^ DL]);
    #pragma unroll
    for (int t = 0; t < 16; ++t) {
        const bool pt = __popc(t & RL) & 1;
        amp[t] = cmul(pt ? gA1 : gA0, amp[t]) + cmul(pt ? gB1 : gB0, b[t]);
    }
}

// ===========================================================================
// qprep (unchanged from r11)
// ===========================================================================
__global__ __launch_bounds__(256)
void qprep(const float* __restrict__ x, const float* __restrict__ theta,
           float* __restrict__ enh,
           const float* __restrict__ W_in, const float* __restrict__ W_h,
           const float* __restrict__ W_out,
           u16* __restrict__ win_hi, u16* __restrict__ win_lo,
           u16* __restrict__ wh_hi,  u16* __restrict__ wh_lo,
           u16* __restrict__ wout_hi,u16* __restrict__ wout_lo) {
    const int tid = threadIdx.x;
    const int bid = blockIdx.x;

    if (bid >= QBLOCKS) {
        const int i = (bid - QBLOCKS) * 256 + tid;
        float v; u16 *ph, *pl; int off;
        if (i < 32768)        { v = W_in[i];          ph = win_hi;  pl = win_lo;  off = i; }
        else if (i < 557056)  { off = i - 32768;  v = W_h[off];   ph = wh_hi;   pl = wh_lo;  }
        else                  { off = i - 557056; v = W_out[off]; ph = wout_hi; pl = wout_lo; }
        const u16 hi = f2bf(v);
        const u16 lo = f2bf(v - bf2f(hi));
        ph[off] = hi; pl[off] = lo;
        return;
    }

    __shared__ f32x2 gbuf[20][4];
    if (tid < 20) {
        const int base = tid * 3;
        float s1, c1, s2, c2, sz, cz;
        sincosf(0.5f * theta[base + 0], &s1, &c1);
        sincosf(0.5f * theta[base + 1], &s2, &c2);
        sincosf(0.5f * theta[base + 2], &sz, &cz);
        f32x2 m00 = (f32x2){ c2*c1,  s2*s1};
        f32x2 m01 = (f32x2){-s2*c1, -c2*s1};
        f32x2 m10 = (f32x2){ s2*c1, -c2*s1};
        f32x2 m11 = (f32x2){ c2*c1, -s2*s1};
        f32x2 e0 = (f32x2){cz, -sz}, e1 = (f32x2){cz, sz};
        gbuf[tid][0] = cmul(e0, m00);
        gbuf[tid][1] = cmul(e0, m01);
        gbuf[tid][2] = cmul(e1, m10);
        gbuf[tid][3] = cmul(e1, m11);
    }
    __syncthreads();

    const int lane = tid & 63;
    const int s = bid * 4 + (tid >> 6);
    const float xr = x[s * FEAT + lane];

    const float inv = 1.0f / sqrtf(fmaf(xr, xr, 1.0f));
    const float cq = inv, sq = xr * inv;

    float csv[10], snv[10];
    #pragma unroll
    for (int i = 0; i < 10; ++i) {
        csv[i] = __shfl(cq, i, 64);
        snv[i] = __shfl(sq, i, 64);
    }

    float lf = ((lane >> 0) & 1) ? snv[4] : csv[4];
    lf *= ((lane >> 1) & 1) ? snv[5] : csv[5];
    lf *= ((lane >> 2) & 1) ? snv[6] : csv[6];
    lf *= ((lane >> 3) & 1) ? snv[7] : csv[7];
    lf *= ((lane >> 4) & 1) ? snv[8] : csv[8];
    lf *= ((lane >> 5) & 1) ? snv[9] : csv[9];
    float l01[4], l23[4];
    l01[0] = csv[0]*csv[1]; l01[1] = snv[0]*csv[1];
    l01[2] = csv[0]*snv[1]; l01[3] = snv[0]*snv[1];
    l23[0] = csv[2]*csv[3]; l23[1] = snv[2]*csv[3];
    l23[2] = csv[2]*snv[3]; l23[3] = snv[2]*snv[3];

    f32x2 amp[16];
    #pragma unroll
    for (int t = 0; t < 16; ++t)
        amp[t] = (f32x2){lf * l01[t & 3] * l23[(t >> 2) & 3], 0.f};

    {
        const f32x2* g1 = &gbuf[0][0];
        #define ROT(Q) rot_gate<Q>(amp, g1[Q*4+0], g1[Q*4+1], g1[Q*4+2], g1[Q*4+3], lane);
        ROT(0) ROT(1) ROT(2) ROT(3) ROT(4) ROT(5) ROT(6) ROT(7) ROT(8) ROT(9)
        #undef ROT
    }
    {
        const f32x2* g2 = &gbuf[10][0];
        #define ROT2(Q, D, R) rot2<D, R>(amp, g2[Q*4+0], g2[Q*4+1], g2[Q*4+2], g2[Q*4+3], lane);
        ROT2(0, 0x003, 0x3FE)
        ROT2(1, 0x006, 0x003)
        ROT2(2, 0x00C, 0x007)
        ROT2(3, 0x018, 0x00F)
        ROT2(4, 0x030, 0x01F)
        ROT2(5, 0x060, 0x03F)
        ROT2(6, 0x0C0, 0x07F)
        ROT2(7, 0x180, 0x0FF)
        ROT2(8, 0x300, 0x1FF)
        ROT2(9, 0x203, 0x3FF)
        #undef ROT2
    }

    float p[16];
    #pragma unroll
    for (int t = 0; t < 16; ++t) p[t] = amp[t].x*amp[t].x + amp[t].y*amp[t].y;

    float S5 = 0.f, SA = 0.f, SB = 0.f, SD = 0.f;
    #pragma unroll
    for (int t = 0; t < 16; ++t) {
        S5 += (__popc(t & 0x5) & 1) ? -p[t] : p[t];
        SA += (__popc(t & 0xA) & 1) ? -p[t] : p[t];
        SB += (__popc(t & 0xB) & 1) ? -p[t] : p[t];
        SD += (__popc(t & 0xD) & 1) ? -p[t] : p[t];
    }
    float o[10];
    o[0] = SB; o[1] = SD; o[2] = SA; o[3] = S5; o[4] = SA;
    o[5] = S5; o[6] = SA; o[7] = S5; o[8] = SA; o[9] = S5;
    if (__popc(lane & 0x2A) & 1) o[0] = -o[0];
    if (__popc(lane & 0x3F) & 1) o[1] = -o[1];
    if (__popc(lane & 0x3F) & 1) o[2] = -o[2];
    if (__popc(lane & 0x3F) & 1) o[3] = -o[3];
    if (__popc(lane & 0x3E) & 1) o[4] = -o[4];
    if (__popc(lane & 0x3D) & 1) o[5] = -o[5];
    if (__popc(lane & 0x3A) & 1) o[6] = -o[6];
    if (__popc(lane & 0x35) & 1) o[7] = -o[7];
    if (__popc(lane & 0x2A) & 1) o[8] = -o[8];
    if (__popc(lane & 0x15) & 1) o[9] = -o[9];

    #pragma unroll
    for (int i = 0; i < 10; ++i) {
        #pragma unroll
        for (int b = 1; b < 64; b <<= 1) o[i] += __shfl_xor(o[i], b, 64);
    }
    float outv = xr;
    #pragma unroll
    for (int i = 0; i < 10; ++i) if (lane == i) outv = o[i];
    enh[s * FEAT + lane] = outv;
}

// ===========================================================================
// MFMA MLP — 64-row tile, 16 waves x NT=2, P/Q W double-buffer (~115 regs)
//   LDS h hi/lo [64][512] bf16 (128 KB), XOR-swizzled:
//     (m,k) stored at m*K + ((k>>3)^(m&7))*8 + (k&7)
// ===========================================================================
__device__ __forceinline__ float fast_tanh(float x) {
    const float e = __expf(2.0f * x);
    return 1.0f - 2.0f * __builtin_amdgcn_rcpf(e + 1.0f);
}

#define MT 4   // 4 m-tiles of 16 = 64 rows

template<int K, int NT>
__device__ __forceinline__ void gemm_frag(
        const u16* __restrict__ Whi, const u16* __restrict__ Wlo,
        const u16* hHi, const u16* hLo, int lane, int colbase,
        f32x4_t (&acc)[MT][NT]) {
    constexpr int KS = K / 32;
    const int l15 = lane & 15, l4 = lane >> 4;

    #pragma unroll
    for (int mt = 0; mt < MT; ++mt)
        #pragma unroll
        for (int nt = 0; nt < NT; ++nt) acc[mt][nt] = (f32x4_t)0.f;

    int woff[NT];
    #pragma unroll
    for (int nt = 0; nt < NT; ++nt)
        woff[nt] = (colbase + nt * 16 + l15) * K + l4 * 8;

    bf16x8_t pH[NT], pL[NT], qH[NT], qL[NT];
    #pragma unroll
    for (int nt = 0; nt < NT; ++nt) {
        pH[nt] = *(const bf16x8_t*)&Whi[woff[nt]];
        pL[nt] = *(const bf16x8_t*)&Wlo[woff[nt]];
        qH[nt] = *(const bf16x8_t*)&Whi[woff[nt] + 32];
        qL[nt] = *(const bf16x8_t*)&Wlo[woff[nt] + 32];
    }

    int ks = 0;
    #pragma unroll 1
    for (; ks + 2 < KS; ks += 2) {
        {
            bf16x8_t aH[MT], aL[MT];
            #pragma unroll
            for (int mt = 0; mt < MT; ++mt) {
                const int m = mt * 16 + l15;
                const int off = m * K + (((ks * 4 + l4) ^ (m & 7)) * 8);
                aH[mt] = *(const bf16x8_t*)&hHi[off];
                aL[mt] = *(const bf16x8_t*)&hLo[off];
            }
            #pragma unroll
            for (int nt = 0; nt < NT; ++nt)
                #pragma unroll
                for (int mt = 0; mt < MT; ++mt) {
                    acc[mt][nt] = __builtin_amdgcn_mfma_f32_16x16x32_bf16(aH[mt], pH[nt], acc[mt][nt], 0, 0, 0);
                    acc[mt][nt] = __builtin_amdgcn_mfma_f32_16x16x32_bf16(aH[mt], pL[nt], acc[mt][nt], 0, 0, 0);
                    acc[mt][nt] = __builtin_amdgcn_mfma_f32_16x16x32_bf16(aL[mt], pH[nt], acc[mt][nt], 0, 0, 0);
                }
        }
        #pragma unroll
        for (int nt = 0; nt < NT; ++nt) {
            pH[nt] = *(const bf16x8_t*)&Whi[woff[nt] + (ks + 2) * 32];
            pL[nt] = *(const bf16x8_t*)&Wlo[woff[nt] + (ks + 2) * 32];
        }
        {
            bf16x8_t aH[MT], aL[MT];
            #pragma unroll
            for (int mt = 0; mt < MT; ++mt) {
                const int m = mt * 16 + l15;
                const int off = m * K + ((((ks + 1) * 4 + l4) ^ (m & 7)) * 8);
                aH[mt] = *(const bf16x8_t*)&hHi[off];
                aL[mt] = *(const bf16x8_t*)&hLo[off];
            }
            #pragma unroll
            for (int nt = 0; nt < NT; ++nt)
                #pragma unroll
                for (int mt = 0; mt < MT; ++mt) {
                    acc[mt][nt] = __builtin_amdgcn_mfma_f32_16x16x32_bf16(aH[mt], qH[nt], acc[mt][nt], 0, 0, 0);
                    acc[mt][nt] = __builtin_amdgcn_mfma_f32_16x16x32_bf16(aH[mt], qL[nt], acc[mt][nt], 0, 0, 0);
                    acc[mt][nt] = __builtin_amdgcn_mfma_f32_16x16x32_bf16(aL[mt], qH[nt], acc[mt][nt], 0, 0, 0);
                }
        }
        #pragma unroll
        for (int nt = 0; nt < NT; ++nt) {
            qH[nt] = *(const bf16x8_t*)&Whi[woff[nt] + (ks + 3) * 32];
            qL[nt] = *(const bf16x8_t*)&Wlo[woff[nt] + (ks + 3) * 32];
        }
    }
    {
        bf16x8_t aH[MT], aL[MT];
        #pragma unroll
        for (int mt = 0; mt < MT; ++mt) {
            const int m = mt * 16 + l15;
            const int off = m * K + (((ks * 4 + l4) ^ (m & 7)) * 8);
            aH[mt] = *(const bf16x8_t*)&hHi[off];
            aL[mt] = *(const bf16x8_t*)&hLo[off];
        }
        #pragma unroll
        for (int nt = 0; nt < NT; ++nt)
            #pragma unroll
            for (int mt = 0; mt < MT; ++mt) {
                acc[mt][nt] = __builtin_amdgcn_mfma_f32_16x16x32_bf16(aH[mt], pH[nt], acc[mt][nt], 0, 0, 0);
                acc[mt][nt] = __builtin_amdgcn_mfma_f32_16x16x32_bf16(aH[mt], pL[nt], acc[mt][nt], 0, 0, 0);
                acc[mt][nt] = __builtin_amdgcn_mfma_f32_16x16x32_bf16(aL[mt], pH[nt], acc[mt][nt], 0, 0, 0);
            }
        #pragma unroll
        for (int mt = 0; mt < MT; ++mt) {
            const int m = mt * 16 + l15;
            const int off = m * K + ((((ks + 1) * 4 + l4) ^ (m & 7)) * 8);
            aH[mt] = *(const bf16x8_t*)&hHi[off];
            aL[mt] = *(const bf16x8_t*)&hLo[off];
        }
        #pragma unroll
        for (int nt = 0; nt < NT; ++nt)
            #pragma unroll
            for (int mt = 0; mt < MT; ++mt) {
                acc[mt][nt] = __builtin_amdgcn_mfma_f32_16x16x32_bf16(aH[mt], qH[nt], acc[mt][nt], 0, 0, 0);
                acc[mt][nt] = __builtin_amdgcn_mfma_f32_16x16x32_bf16(aH[mt], qL[nt], acc[mt][nt], 0, 0, 0);
                acc[mt][nt] = __builtin_amdgcn_mfma_f32_16x16x32_bf16(aL[mt], qH[nt], acc[mt][nt], 0, 0, 0);
            }
    }
}

template<int NT>
__device__ __forceinline__ void write_h(
        f32x4_t (&acc)[MT][NT], const float* __restrict__ bias,
        u16* hHi, u16* hLo, int lane, int colbase) {
    const int l15 = lane & 15, l4 = lane >> 4;
    #pragma unroll
    for (int nt = 0; nt < NT; ++nt) {
        const int n = colbase + nt * 16 + l15;
        const float b = bias[n];
        #pragma unroll
        for (int mt = 0; mt < MT; ++mt)
            #pragma unroll
            for (int r = 0; r < 4; ++r) {
                const int m = mt * 16 + l4 * 4 + r;
                const float v = fast_tanh(acc[mt][nt][r] + b);
                const u16 hi = f2bf(v);
                const u16 lo = f2bf(v - bf2f(hi));
                const int blk = (n >> 3) ^ (m & 7);
                const int off = m * 512 + blk * 8 + (n & 7);
                hHi[off] = hi; hLo[off] = lo;
            }
    }
}

__global__ __attribute__((amdgpu_waves_per_eu(2, 2))) __launch_bounds__(1024)
void mlpkernel(const float* __restrict__ enh,
               const u16* __restrict__ win_hi, const u16* __restrict__ win_lo,
               const float* __restrict__ b_in,
               const u16* __restrict__ wh_hi,  const u16* __restrict__ wh_lo,
               const float* __restrict__ b_h,
               const u16* __restrict__ wout_hi,const u16* __restrict__ wout_lo,
               const float* __restrict__ b_out,
               float* __restrict__ out) {
    __shared__ u16 hHi[64 * 512];           // 64 KB
    __shared__ u16 hLo[64 * 512];           // 64 KB
    const int tid = threadIdx.x;
    const int lane = tid & 63, w = tid >> 6;      // 16 waves
    const int row0 = blockIdx.x * 64;

    // ---- stage enhanced[64][64] -> LDS hi/lo (1024 thr x 4 floats) ----
    {
        const int r = tid >> 4, c0 = (tid & 15) * 4;
        const float4 v = *(const float4*)&enh[(row0 + r) * FEAT + c0];
        const float vv[4] = {v.x, v.y, v.z, v.w};
        u16 vh[4], vl[4];
        #pragma unroll
        for (int j = 0; j < 4; ++j) {
            vh[j] = f2bf(vv[j]);
            vl[j] = f2bf(vv[j] - bf2f(vh[j]));
        }
        const int off = r * 64 + (((c0 >> 3) ^ (r & 7)) * 8) + (c0 & 7);
        *(ushort4*)&hHi[off] = *(ushort4*)vh;
        *(ushort4*)&hLo[off] = *(ushort4*)vl;
    }
    __syncthreads();

    f32x4_t acc[MT][2];
    gemm_frag<64, 2>(win_hi, win_lo, hHi, hLo, lane, w * 32, acc);
    __syncthreads();
    write_h<2>(acc, b_in, hHi, hLo, lane, w * 32);
    __syncthreads();
    gemm_frag<512, 2>(wh_hi, wh_lo, hHi, hLo, lane, w * 32, acc);
    __syncthreads();
    write_h<2>(acc, b_h, hHi, hLo, lane, w * 32);
    __syncthreads();
    gemm_frag<512, 2>(wh_hi + 262144, wh_lo + 262144, hHi, hLo, lane, w * 32, acc);
    __syncthreads();
    write_h<2>(acc, b_h + 512, hHi, hLo, lane, w * 32);
    __syncthreads();

    // layer 4: 128 cols -> waves 0..7 only (others join barriers)
    f32x4_t acc2[MT][1];
    if (w < 8) {
        gemm_frag<512, 1>(wout_hi, wout_lo, hHi, hLo, lane, w * 16, acc2);
    }
    __syncthreads();

    float* f = (float*)hHi;     // reuse LDS: out tile [64][128] fp32 (32 KB)
    if (w < 8) {
        const int l15 = lane & 15, l4 = lane >> 4;
        const int n = w * 16 + l15;
        const float b = b_out[n];
        #pragma unroll
        for (int mt = 0; mt < MT; ++mt)
            #pragma unroll
            for (int r = 0; r < 4; ++r) {
                const int m = mt * 16 + l4 * 4 + r;
                f[m * 128 + n] = acc2[mt][0][r] + b;
            }
    }
    __syncthreads();

    // ---- log-prob epilogue: 4 rows per wave (16 waves x 4 = 64) ----
    const float HALF_LOG2PI = 0.9189385332046727f;
    #pragma unroll
    for (int rr = 0; rr < 4; ++rr) {
        const int row = w * 4 + rr;
        const float shift = f[row * 128 + lane];
        const float ls    = f[row * 128 + 64 + lane];
        const float e     = enh[(row0 + row) * FEAT + lane];
        const float z = (e - shift) * __expf(-ls);
        float term = fmaf(-0.5f * z, z, -HALF_LOG2PI) - ls;
        #pragma unroll
        for (int b = 1; b < 64; b <<= 1) term += __shfl_xor(term, b, 64);
        if (lane == 0) out[row0 + row] = term;
    }
}

extern "C" void kernel_launch(void* const* d_in, const int* in_sizes, int n_in,
                              void* d_out, int out_size, void* d_ws, size_t ws_size,
                              hipStream_t stream) {
    const float* x     = (const float*)d_in[0];
    const float* theta = (const float*)d_in[1];
    const float* W_in  = (const float*)d_in[2];
    const float* b_in  = (const float*)d_in[3];
    const float* W_h   = (const float*)d_in[4];
    const float* b_h   = (const float*)d_in[5];
    const float* W_out = (const float*)d_in[6];
    const float* b_out = (const float*)d_in[7];
    float* out = (float*)d_out;

    float* enh = (float*)d_ws;                                    // 8 MB
    u16* wbuf = (u16*)((char*)d_ws + (size_t)N_SAMPLES * FEAT * 4);
    u16* win_hi  = wbuf;
    u16* win_lo  = win_hi + 32768;
    u16* wh_hi   = win_lo + 32768;
    u16* wh_lo   = wh_hi + 524288;
    u16* wout_hi = wh_lo + 524288;
    u16* wout_lo = wout_hi + 65536;

    qprep<<<dim3(QBLOCKS + PREPBLOCKS), dim3(256), 0, stream>>>(
        x, theta, enh, W_in, W_h, W_out,
        win_hi, win_lo, wh_hi, wh_lo, wout_hi, wout_lo);
    mlpkernel<<<dim3(N_SAMPLES / 64), dim3(1024), 0, stream>>>(
        enh, win_hi, win_lo, b_in, wh_hi, wh_lo, b_h, wout_hi, wout_lo, b_out, out);
}